// Round 1
// baseline (226.633 us; speedup 1.0000x reference)
//
#include <hip/hip_runtime.h>
#include <hip/hip_fp16.h>
#include <stdint.h>

#define I_DIM 2048
#define O_DIM 2048
#define B_DIM 4096
#define KOUT 16

typedef int i32x4 __attribute__((ext_vector_type(4)));

#define TO_LDS(p) ((__attribute__((address_space(3))) void*)(p))
#define TO_GLB(p) ((const __attribute__((address_space(1))) void*)(p))

// ---------------- Stage 1: column absmax of W (O_DIM x I_DIM) ----------------
__global__ void colmax_kernel(const float* __restrict__ W, unsigned* __restrict__ cm) {
  int j = blockIdx.x * 256 + threadIdx.x;       // column
  int i0 = blockIdx.y * 128;                    // row chunk
  float m = 0.0f;
  const float* p = W + (size_t)i0 * I_DIM + j;
  for (int i = 0; i < 128; ++i)
    m = fmaxf(m, fabsf(p[(size_t)i * I_DIM]));
  atomicMax(cm + j, __float_as_uint(m));        // nonneg floats: uint order == float order
}

// ---------------- Stage 2: top-16 indices + keep mask ----------------
__global__ void topk_kernel(const unsigned* __restrict__ cm, int* __restrict__ idx,
                            float* __restrict__ keep) {
  __shared__ float vals[I_DIM];
  __shared__ float rmax[256];
  __shared__ int ridx[256];
  int t = threadIdx.x;
  for (int j = t; j < I_DIM; j += 256) { vals[j] = __uint_as_float(cm[j]); keep[j] = 1.0f; }
  __syncthreads();
  for (int k = 0; k < KOUT; ++k) {
    float m = -1.0f; int mi = 0;
    for (int j = t; j < I_DIM; j += 256)
      if (vals[j] > m) { m = vals[j]; mi = j; }
    rmax[t] = m; ridx[t] = mi;
    __syncthreads();
    for (int s = 128; s > 0; s >>= 1) {
      if (t < s && rmax[t + s] > rmax[t]) { rmax[t] = rmax[t + s]; ridx[t] = ridx[t + s]; }
      __syncthreads();
    }
    if (t == 0) { int w = ridx[0]; idx[k] = w; vals[w] = -1.0f; keep[w] = 0.0f; }
    __syncthreads();
  }
}

// ---------------- Stage 3a: quantize W rows; extract w_unq[k][o] ----------------
__global__ void quant_w_kernel(const float* __restrict__ W, const float* __restrict__ keep,
                               const int* __restrict__ idx, signed char* __restrict__ wq,
                               float* __restrict__ wmax, float* __restrict__ wunq) {
  __shared__ float row[I_DIM];
  __shared__ float red[256];
  int o = blockIdx.x;
  int t = threadIdx.x;
  const float* Wr = W + (size_t)o * I_DIM;
  if (t < KOUT) wunq[(size_t)t * O_DIM + o] = Wr[idx[t]];
  float m = 0.0f;
  for (int j = t; j < I_DIM; j += 256) {
    float v = Wr[j] * keep[j];
    row[j] = v;
    m = fmaxf(m, fabsf(v));
  }
  red[t] = m;
  __syncthreads();
  for (int s = 128; s > 0; s >>= 1) {
    if (t < s) red[t] = fmaxf(red[t], red[t + s]);
    __syncthreads();
  }
  float mm = red[0];
  if (t == 0) wmax[o] = mm;
  float sc = 127.0f / mm;                       // match ref: scale first, then mul, then trunc
  for (int j = t; j < I_DIM; j += 256)
    wq[(size_t)o * I_DIM + j] = (signed char)(int)(row[j] * sc);
}

// ---------------- Stage 3b: quantize X rows; extract x_unq[b][k] ----------------
__global__ void quant_x_kernel(const float* __restrict__ X, const float* __restrict__ keep,
                               const int* __restrict__ idx, signed char* __restrict__ xq,
                               float* __restrict__ xmax, float* __restrict__ xunq) {
  __shared__ float row[I_DIM];
  __shared__ float red[256];
  int b = blockIdx.x;
  int t = threadIdx.x;
  const float* Xr = X + (size_t)b * I_DIM;
  if (t < KOUT) xunq[(size_t)b * KOUT + t] = Xr[idx[t]];
  float m = 0.0f;
  for (int j = t; j < I_DIM; j += 256) {
    float v = Xr[j] * keep[j];
    row[j] = v;
    m = fmaxf(m, fabsf(v));
  }
  red[t] = m;
  __syncthreads();
  for (int s = 128; s > 0; s >>= 1) {
    if (t < s) red[t] = fmaxf(red[t], red[t + s]);
    __syncthreads();
  }
  float mm = red[0];
  if (t == 0) xmax[b] = mm;
  float sc = 127.0f / mm;
  for (int j = t; j < I_DIM; j += 256)
    xq[(size_t)b * I_DIM + j] = (signed char)(int)(row[j] * sc);
}

// ---------------- Stage 4: int8 GEMM (C = Xq * Wq^T) + fused epilogue ----------------
__global__ __launch_bounds__(256) void gemm_kernel(
    const signed char* __restrict__ Aq,   // M x K (x_q)
    const signed char* __restrict__ Bq,   // N x K (w_q)
    const float* __restrict__ xmaxg,      // M
    const float* __restrict__ wmaxg,      // N
    const float* __restrict__ xunqg,      // M x 16
    const float* __restrict__ wunqg,      // 16 x N
    const float* __restrict__ biasg,      // N
    float* __restrict__ out) {            // M x N
  constexpr int N = O_DIM, K = I_DIM;
  __shared__ __align__(16) signed char smem[18432];
  signed char* As = smem;                 // 128 x 64 i8
  signed char* Bs = smem + 8192;          // 128 x 64 i8

  const int tid = threadIdx.x;
  const int lane = tid & 63;
  const int wave = tid >> 6;
  const int wm = (wave & 1) * 64;
  const int wn = (wave >> 1) * 64;
  const int m0 = blockIdx.y * 128;
  const int n0 = blockIdx.x * 128;
  const int row0 = tid >> 2;              // staging: (tid*16)/64
  const int col0 = (tid & 3) * 16;
  const int fm = lane & 15;
  const int fk = (lane >> 4) * 16;

  i32x4 acc[4][4] = {};

  for (int kt = 0; kt < K; kt += 64) {
    const signed char* ga0 = Aq + (size_t)(m0 + row0) * K + kt + col0;
    const signed char* gb0 = Bq + (size_t)(n0 + row0) * K + kt + col0;
    __builtin_amdgcn_global_load_lds(TO_GLB(ga0), TO_LDS(As + wave * 1024), 16, 0, 0);
    __builtin_amdgcn_global_load_lds(TO_GLB(ga0 + (size_t)64 * K), TO_LDS(As + 4096 + wave * 1024), 16, 0, 0);
    __builtin_amdgcn_global_load_lds(TO_GLB(gb0), TO_LDS(Bs + wave * 1024), 16, 0, 0);
    __builtin_amdgcn_global_load_lds(TO_GLB(gb0 + (size_t)64 * K), TO_LDS(Bs + 4096 + wave * 1024), 16, 0, 0);
    __syncthreads();
    i32x4 af[4], bf[4];
#pragma unroll
    for (int i = 0; i < 4; ++i) af[i] = *(const i32x4*)(As + (wm + i * 16 + fm) * 64 + fk);
#pragma unroll
    for (int i = 0; i < 4; ++i) bf[i] = *(const i32x4*)(Bs + (wn + i * 16 + fm) * 64 + fk);
#pragma unroll
    for (int i = 0; i < 4; ++i)
#pragma unroll
      for (int j = 0; j < 4; ++j)
        acc[i][j] = __builtin_amdgcn_mfma_i32_16x16x64_i8(af[i], bf[j], acc[i][j], 0, 0, 0);
    __syncthreads();
  }

  // ---- epilogue: reuse LDS for outlier data / scales ----
  float* xu  = (float*)smem;              // 128 x 16
  float* wu  = (float*)(smem + 8192);     // 16 x 128
  float* xm  = (float*)(smem + 16384);    // 128
  float* wmx = (float*)(smem + 16896);    // 128
  float* bsh = (float*)(smem + 17408);    // 128
  for (int i = tid; i < 128 * KOUT; i += 256) xu[i] = xunqg[(size_t)m0 * KOUT + i];
  for (int i = tid; i < 128 * KOUT; i += 256) {
    int k = i >> 7, c = i & 127;
    wu[i] = wunqg[(size_t)k * N + n0 + c];
  }
  if (tid < 128) {
    xm[tid]  = xmaxg[m0 + tid];
    wmx[tid] = wmaxg[n0 + tid];
    bsh[tid] = biasg[n0 + tid];
  }
  __syncthreads();

#pragma unroll
  for (int i = 0; i < 4; ++i) {
#pragma unroll
    for (int j = 0; j < 4; ++j) {
      int cl = wn + j * 16 + fm;
      float wmv = wmx[cl];
      float bv = bsh[cl];
#pragma unroll
      for (int r = 0; r < 4; ++r) {
        int rl = wm + i * 16 + (lane >> 4) * 4 + r;
        float v = (float)acc[i][j][r] / 16129.0f;   // IEEE div, matches ref
        v = __half2float(__float2half(v));          // fp16 round-trip (RN), matches ref
        float res = v * (xm[rl] * wmv) + bv;
#pragma unroll
        for (int k = 0; k < KOUT; ++k) res += xu[rl * KOUT + k] * wu[k * 128 + cl];
        out[(size_t)(m0 + rl) * N + (n0 + cl)] = res;
      }
    }
  }
}

extern "C" void kernel_launch(void* const* d_in, const int* in_sizes, int n_in,
                              void* d_out, int out_size, void* d_ws, size_t ws_size,
                              hipStream_t stream) {
  const float* x    = (const float*)d_in[0];   // 4096 x 2048
  const float* w    = (const float*)d_in[1];   // 2048 x 2048
  const float* bias = (const float*)d_in[2];   // 2048
  float* out = (float*)d_out;
  char* ws = (char*)d_ws;

  unsigned* cm     = (unsigned*)(ws + 0);        // 8 KB
  int* idx         = (int*)(ws + 8192);          // 64 B
  float* keep      = (float*)(ws + 8320);        // 8 KB
  float* w_max     = (float*)(ws + 16512);       // 8 KB
  float* x_max     = (float*)(ws + 24704);       // 16 KB
  float* w_unq     = (float*)(ws + 41088);       // 16*2048*4 = 128 KB
  float* x_unq     = (float*)(ws + 172160);      // 4096*16*4 = 256 KB
  signed char* w_q = (signed char*)(ws + 434304);   // 4 MB
  signed char* x_q = (signed char*)(ws + 4628608);  // 8 MB  (total ~12.4 MB)

  hipMemsetAsync(cm, 0, 8192, stream);
  colmax_kernel<<<dim3(8, 16), 256, 0, stream>>>(w, cm);
  topk_kernel<<<1, 256, 0, stream>>>(cm, idx, keep);
  quant_w_kernel<<<O_DIM, 256, 0, stream>>>(w, keep, idx, w_q, w_max, w_unq);
  quant_x_kernel<<<B_DIM, 256, 0, stream>>>(x, keep, idx, x_q, x_max, x_unq);
  gemm_kernel<<<dim3(O_DIM / 128, B_DIM / 128), 256, 0, stream>>>(
      x_q, w_q, x_max, w_max, x_unq, w_unq, bias, out);
}

// Round 2
// 148.818 us; speedup vs baseline: 1.5229x; 1.5229x over previous
//
#include <hip/hip_runtime.h>
#include <hip/hip_fp16.h>
#include <stdint.h>

#define I_DIM 2048
#define O_DIM 2048
#define B_DIM 4096
#define KOUT 16

typedef int i32x4 __attribute__((ext_vector_type(4)));
typedef float f32x4 __attribute__((ext_vector_type(4)));
typedef _Float16 f16x8 __attribute__((ext_vector_type(8)));

#define TO_LDS(p) ((__attribute__((address_space(3))) void*)(p))
#define TO_GLB(p) ((const __attribute__((address_space(1))) void*)(p))

// ---------------- Stage 1: column absmax of W (O_DIM x I_DIM) ----------------
__global__ void colmax_kernel(const float* __restrict__ W, unsigned* __restrict__ cm) {
  int j = blockIdx.x * 256 + threadIdx.x;       // column
  int i0 = blockIdx.y * 64;                     // row chunk
  float m = 0.0f;
  const float* p = W + (size_t)i0 * I_DIM + j;
  for (int i = 0; i < 64; ++i)
    m = fmaxf(m, fabsf(p[(size_t)i * I_DIM]));
  atomicMax(cm + j, __float_as_uint(m));        // nonneg floats: uint order == float order
}

// ---------------- Stage 2: top-16 indices + keep mask (register-resident) ----------------
__global__ void topk_kernel(const unsigned* __restrict__ cm, int* __restrict__ idx,
                            float* __restrict__ keep) {
  int t = threadIdx.x;                          // 256 threads, 8 vals each
  const float4* c4 = (const float4*)cm;
  float4 a = c4[t * 2], b = c4[t * 2 + 1];
  float v[8] = {a.x, a.y, a.z, a.w, b.x, b.y, b.z, b.w};
  for (int j = t; j < I_DIM; j += 256) keep[j] = 1.0f;
  __shared__ float wm_[4];
  __shared__ int wi_[4];
  __shared__ int sel;
  for (int k = 0; k < KOUT; ++k) {
    float m = v[0]; int mi = 0;
#pragma unroll
    for (int r = 1; r < 8; ++r) if (v[r] > m) { m = v[r]; mi = r; }
    int gi = t * 8 + mi;
#pragma unroll
    for (int s = 32; s; s >>= 1) {
      float om = __shfl_down(m, s);
      int oi = __shfl_down(gi, s);
      if (om > m) { m = om; gi = oi; }
    }
    if ((t & 63) == 0) { wm_[t >> 6] = m; wi_[t >> 6] = gi; }
    __syncthreads();
    if (t == 0) {
      float bm = wm_[0]; int bi = wi_[0];
      for (int w2 = 1; w2 < 4; ++w2) if (wm_[w2] > bm) { bm = wm_[w2]; bi = wi_[w2]; }
      idx[k] = bi; keep[bi] = 0.0f; sel = bi;
    }
    __syncthreads();
    if (t == (sel >> 3)) v[sel & 7] = -1.0f;
  }
}

// ---------------- Stage 3: quantize W rows and X rows (merged) ----------------
// block b < O_DIM: weight row b.  block b >= O_DIM: x row (b - O_DIM).
__global__ __launch_bounds__(256) void quant_kernel(
    const float* __restrict__ X, const float* __restrict__ W,
    const float* __restrict__ keep, const int* __restrict__ idx,
    signed char* __restrict__ xq, signed char* __restrict__ wq,
    float* __restrict__ xmax, float* __restrict__ wmax,
    _Float16* __restrict__ xunqh,   // [B][32] halves (k padded 16->32 w/ zeros)
    _Float16* __restrict__ wunqh) { // [O][32] halves
  int b = blockIdx.x;
  int t = threadIdx.x;
  bool isW = b < O_DIM;
  int r = isW ? b : (b - O_DIM);
  const float* src = isW ? (W + (size_t)r * I_DIM) : (X + (size_t)r * I_DIM);
  const float4* s4 = (const float4*)src;
  const float4* k4 = (const float4*)keep;
  float4 v0 = s4[t], v1 = s4[t + 256];
  float4 k0 = k4[t], k1 = k4[t + 256];
  v0.x *= k0.x; v0.y *= k0.y; v0.z *= k0.z; v0.w *= k0.w;
  v1.x *= k1.x; v1.y *= k1.y; v1.z *= k1.z; v1.w *= k1.w;
  float m = fmaxf(fmaxf(fmaxf(fabsf(v0.x), fabsf(v0.y)), fmaxf(fabsf(v0.z), fabsf(v0.w))),
                  fmaxf(fmaxf(fabsf(v1.x), fabsf(v1.y)), fmaxf(fabsf(v1.z), fabsf(v1.w))));
#pragma unroll
  for (int s = 32; s; s >>= 1) m = fmaxf(m, __shfl_xor(m, s));
  __shared__ float red[4];
  if ((t & 63) == 0) red[t >> 6] = m;
  __syncthreads();
  m = fmaxf(fmaxf(red[0], red[1]), fmaxf(red[2], red[3]));
  float sc = 127.0f / m;                        // match ref: scale first, then mul, then trunc
  unsigned p0 = (unsigned char)(signed char)(int)(v0.x * sc)
              | ((unsigned)(unsigned char)(signed char)(int)(v0.y * sc) << 8)
              | ((unsigned)(unsigned char)(signed char)(int)(v0.z * sc) << 16)
              | ((unsigned)(unsigned char)(signed char)(int)(v0.w * sc) << 24);
  unsigned p1 = (unsigned char)(signed char)(int)(v1.x * sc)
              | ((unsigned)(unsigned char)(signed char)(int)(v1.y * sc) << 8)
              | ((unsigned)(unsigned char)(signed char)(int)(v1.z * sc) << 16)
              | ((unsigned)(unsigned char)(signed char)(int)(v1.w * sc) << 24);
  unsigned* qout = (unsigned*)(isW ? (wq + (size_t)r * I_DIM) : (xq + (size_t)r * I_DIM));
  qout[t] = p0;
  qout[t + 256] = p1;
  if (t == 0) { if (isW) wmax[r] = m; else xmax[r] = m; }
  if (t < KOUT) {
    float ov = src[idx[t]];
    _Float16* u = isW ? (wunqh + (size_t)r * 32) : (xunqh + (size_t)r * 32);
    u[t] = (_Float16)ov;
    u[t + KOUT] = (_Float16)0.0f;               // zero-pad k 16..31
  }
}

// ---------------- Stage 4: int8 GEMM (C = Xq * Wq^T) + fused MFMA epilogue ----------------
__global__ __launch_bounds__(256) void gemm_kernel(
    const signed char* __restrict__ Aq,   // M x K (x_q)
    const signed char* __restrict__ Bq,   // N x K (w_q)
    const float* __restrict__ xmaxg,      // M
    const float* __restrict__ wmaxg,      // N
    const _Float16* __restrict__ xunqh,   // M x 32
    const _Float16* __restrict__ wunqh,   // N x 32
    const float* __restrict__ biasg,      // N
    float* __restrict__ out) {            // M x N
  constexpr int N = O_DIM, K = I_DIM;
  __shared__ __align__(16) signed char smem[16384];
  signed char* As = smem;                 // 128 x 64 i8 (chunk-swizzled)
  signed char* Bs = smem + 8192;

  const int tid = threadIdx.x;
  const int lane = tid & 63;
  const int wave = tid >> 6;
  const int wm = (wave & 1) * 64;
  const int wn = (wave >> 1) * 64;
  const int m0 = blockIdx.y * 128;
  const int n0 = blockIdx.x * 128;
  const int row0 = tid >> 2;              // staging row (0..63 within half-tile)
  // chunk swizzle: LDS slot (r,g) holds global 16B-chunk (g - (r>>1)) & 3
  const int col0 = ((((tid & 3) - (row0 >> 1)) & 3) * 16);
  const int fm = lane & 15;
  const int q = lane >> 4;

  i32x4 acc[4][4] = {};

  for (int kt = 0; kt < K; kt += 64) {
    const signed char* ga0 = Aq + (size_t)(m0 + row0) * K + kt + col0;
    const signed char* gb0 = Bq + (size_t)(n0 + row0) * K + kt + col0;
    __builtin_amdgcn_global_load_lds(TO_GLB(ga0), TO_LDS(As + wave * 1024), 16, 0, 0);
    __builtin_amdgcn_global_load_lds(TO_GLB(ga0 + (size_t)64 * K), TO_LDS(As + 4096 + wave * 1024), 16, 0, 0);
    __builtin_amdgcn_global_load_lds(TO_GLB(gb0), TO_LDS(Bs + wave * 1024), 16, 0, 0);
    __builtin_amdgcn_global_load_lds(TO_GLB(gb0 + (size_t)64 * K), TO_LDS(Bs + 4096 + wave * 1024), 16, 0, 0);
    __syncthreads();
    i32x4 af[4], bf[4];
#pragma unroll
    for (int i = 0; i < 4; ++i) {
      int r = wm + i * 16 + fm;
      af[i] = *(const i32x4*)(As + r * 64 + (((q + (r >> 1)) & 3) << 4));
    }
#pragma unroll
    for (int i = 0; i < 4; ++i) {
      int r = wn + i * 16 + fm;
      bf[i] = *(const i32x4*)(Bs + r * 64 + (((q + (r >> 1)) & 3) << 4));
    }
#pragma unroll
    for (int i = 0; i < 4; ++i)
#pragma unroll
      for (int j = 0; j < 4; ++j)
        acc[i][j] = __builtin_amdgcn_mfma_i32_16x16x64_i8(af[i], bf[j], acc[i][j], 0, 0, 0);
    __syncthreads();
  }

  // ---- epilogue: dequant + fp16 round-trip + rank-16 outlier MFMA + bias ----
  f16x8 afh[4], bfh[4];
#pragma unroll
  for (int i = 0; i < 4; ++i)
    afh[i] = *(const f16x8*)(xunqh + (size_t)(m0 + wm + i * 16 + fm) * 32 + q * 8);
#pragma unroll
  for (int j = 0; j < 4; ++j)
    bfh[j] = *(const f16x8*)(wunqh + (size_t)(n0 + wn + j * 16 + fm) * 32 + q * 8);

#pragma unroll
  for (int i = 0; i < 4; ++i) {
    f32x4 xmv = *(const f32x4*)(xmaxg + m0 + wm + i * 16 + q * 4);
#pragma unroll
    for (int j = 0; j < 4; ++j) {
      int cl = n0 + wn + j * 16 + fm;
      float wmv = wmaxg[cl];
      float bv = biasg[cl];
      f32x4 c;
#pragma unroll
      for (int r = 0; r < 4; ++r) {
        float v = (float)acc[i][j][r] / 16129.0f;   // IEEE div, matches ref
        v = __half2float(__float2half(v));          // fp16 round-trip (RN), matches ref
        c[r] = v * (xmv[r] * wmv) + bv;
      }
      c = __builtin_amdgcn_mfma_f32_16x16x32_f16(afh[i], bfh[j], c, 0, 0, 0);
#pragma unroll
      for (int r = 0; r < 4; ++r)
        out[(size_t)(m0 + wm + i * 16 + q * 4 + r) * N + cl] = c[r];
    }
  }
}

extern "C" void kernel_launch(void* const* d_in, const int* in_sizes, int n_in,
                              void* d_out, int out_size, void* d_ws, size_t ws_size,
                              hipStream_t stream) {
  const float* x    = (const float*)d_in[0];   // 4096 x 2048
  const float* w    = (const float*)d_in[1];   // 2048 x 2048
  const float* bias = (const float*)d_in[2];   // 2048
  float* out = (float*)d_out;
  char* ws = (char*)d_ws;

  unsigned* cm     = (unsigned*)(ws + 0);        // 8 KB
  int* idx         = (int*)(ws + 8192);          // 128 B
  float* keep      = (float*)(ws + 8320);        // 8 KB
  float* w_max     = (float*)(ws + 16512);       // 8 KB
  float* x_max     = (float*)(ws + 24704);       // 16 KB
  _Float16* x_unqh = (_Float16*)(ws + 41088);    // 4096*32*2 = 256 KB
  _Float16* w_unqh = (_Float16*)(ws + 303232);   // 2048*32*2 = 128 KB
  signed char* w_q = (signed char*)(ws + 434304);   // 4 MB
  signed char* x_q = (signed char*)(ws + 4628608);  // 8 MB  (total ~12.4 MB)

  hipMemsetAsync(cm, 0, 8192, stream);
  colmax_kernel<<<dim3(8, 32), 256, 0, stream>>>(w, cm);
  topk_kernel<<<1, 256, 0, stream>>>(cm, idx, keep);
  quant_kernel<<<O_DIM + B_DIM, 256, 0, stream>>>(x, w, keep, idx, x_q, w_q,
                                                  x_max, w_max, x_unqh, w_unqh);
  gemm_kernel<<<dim3(O_DIM / 128, B_DIM / 128), 256, 0, stream>>>(
      x_q, w_q, x_max, w_max, x_unqh, w_unqh, bias, out);
}